// Round 1
// baseline (2067.614 us; speedup 1.0000x reference)
//
#include <hip/hip_runtime.h>
#include <math.h>

// Problem constants (match reference: NO=64, H=83, S=4)
#define NO 64
#define H  83
#define HP 84   // padded row stride (16B-aligned float4 rows)
#define SP 4    // species count

// ---------------------------------------------------------------------------
// Repack W1 [S][NO][H] -> w1p [S][NO][HP] with zero pad so rows are 16B-aligned
__global__ void repack_w1(const float* __restrict__ W1, float* __restrict__ w1p) {
    int idx = blockIdx.x * 256 + threadIdx.x;          // over S*NO*HP
    if (idx >= SP * NO * HP) return;
    int j  = idx % HP;
    int sk = idx / HP;                                  // s*NO + k
    w1p[idx] = (j < H) ? W1[sk * H + j] : 0.0f;
}

// ---------------------------------------------------------------------------
// Species histogram (block-aggregated atomics)
__global__ void count_species(const int* __restrict__ sym, unsigned* counts, int n) {
    __shared__ unsigned h[SP];
    if (threadIdx.x < SP) h[threadIdx.x] = 0;
    __syncthreads();
    int i = blockIdx.x * blockDim.x + threadIdx.x;
    if (i < n) atomicAdd(&h[sym[i]], 1u);
    __syncthreads();
    if (threadIdx.x < SP) atomicAdd(&counts[threadIdx.x], h[threadIdx.x]);
}

// Exclusive scan of 4 counts -> cursors
__global__ void scan_species(const unsigned* __restrict__ counts, unsigned* cursors) {
    unsigned acc = 0;
    for (int s = 0; s < SP; ++s) { cursors[s] = acc; acc += counts[s]; }
}

// Scatter atom ids into species-contiguous order (block-aggregated cursor atomics)
__global__ void scatter_atoms(const int* __restrict__ sym, unsigned* cursors,
                              int* __restrict__ sorted, int n) {
    __shared__ unsigned wcnt[8][SP];
    __shared__ unsigned wbase[8][SP];
    int lane = threadIdx.x & 63;
    int wave = threadIdx.x >> 6;
    int atom = blockIdx.x * 512 + threadIdx.x;
    int s = (atom < n) ? sym[atom] : -1;

    unsigned long long own = 0;
    for (int t = 0; t < SP; ++t) {
        unsigned long long m = __ballot(s == t);
        if (s == t) own = m;
        if (lane == 0) wcnt[wave][t] = (unsigned)__popcll(m);
    }
    __syncthreads();
    if (threadIdx.x < SP) {
        int t = threadIdx.x;
        unsigned tot = 0, pre[8];
        for (int w = 0; w < 8; ++w) { pre[w] = tot; tot += wcnt[w][t]; }
        unsigned base = atomicAdd(&cursors[t], tot);
        for (int w = 0; w < 8; ++w) wbase[w][t] = base + pre[w];
    }
    __syncthreads();
    if (atom < n) {
        unsigned rank = (unsigned)__popcll(own & ((1ull << lane) - 1ull));
        sorted[wbase[wave][s] + rank] = atom;
    }
}

// ---------------------------------------------------------------------------
// Main fused kernel: per-atom energy + force (fwd + analytic bwd).
// PADDED=true : W1 comes from ws repack (stride HP, float4 rows), atoms gathered
//               via species-sorted index so waves are species-uniform.
// PADDED=false: fallback, raw W1 (stride H), identity atom order.
template <bool PADDED>
__global__ void atoms_kernel(const int* __restrict__ sorted,   // may be null
                             const int* __restrict__ sym,
                             const float* __restrict__ pos,
                             const float* __restrict__ Wd,     // [3][NO]
                             const float* __restrict__ w1,     // [S][NO][RS]
                             const float* __restrict__ b1,     // [S][H]
                             const float* __restrict__ W2,     // [S][H]
                             const float* __restrict__ b2,     // [S]
                             float* __restrict__ energies,
                             float* __restrict__ forces,
                             int n) {
    int slot = blockIdx.x * 256 + threadIdx.x;
    if (slot >= n) return;
    int atom = (sorted != nullptr) ? sorted[slot] : slot;
    int s = sym[atom];

    float p0 = pos[3 * atom + 0];
    float p1 = pos[3 * atom + 1];
    float p2 = pos[3 * atom + 2];

    constexpr int RS = PADDED ? HP : H;
    const float* w1s = w1 + (size_t)s * NO * RS;
    const float* b1s = b1 + s * H;
    const float* w2s = W2 + s * H;

    // z1 lives fully in registers: every index below is compile-time constant.
    float z1[HP];
#pragma unroll
    for (int j = 0; j < H; ++j) z1[j] = b1s[j];
    z1[H] = 0.0f;

    // ---- phase 1: z1 = b1 + sin(p@Wd) @ W1  (k-outer, rows contiguous) ----
    for (int k = 0; k < NO; ++k) {
        float z0 = p0 * Wd[k] + p1 * Wd[NO + k] + p2 * Wd[2 * NO + k];
        float d = __sinf(z0);
        if (PADDED) {
            const float4* row = reinterpret_cast<const float4*>(w1s + k * HP);
#pragma unroll
            for (int jj = 0; jj < HP / 4; ++jj) {
                float4 w = row[jj];
                z1[4 * jj + 0] = fmaf(d, w.x, z1[4 * jj + 0]);
                z1[4 * jj + 1] = fmaf(d, w.y, z1[4 * jj + 1]);
                z1[4 * jj + 2] = fmaf(d, w.z, z1[4 * jj + 2]);
                z1[4 * jj + 3] = fmaf(d, w.w, z1[4 * jj + 3]);
            }
        } else {
            const float* row = w1s + k * H;
#pragma unroll
            for (int j = 0; j < H; ++j) z1[j] = fmaf(d, row[j], z1[j]);
        }
    }

    // ---- phase 2: SiLU, energy head, and g1 = W2 * silu'(z1) in place ----
    float es = b2[s];
#pragma unroll
    for (int j = 0; j < H; ++j) {
        float z  = z1[j];
        float sg = 1.0f / (1.0f + __expf(-z));
        float w2 = w2s[j];
        es = fmaf(z * sg, w2, es);
        // silu'(z) = sg * (1 + z*(1-sg))
        z1[j] = w2 * sg * fmaf(z, 1.0f - sg, 1.0f);
    }
    z1[H] = 0.0f;   // pad lane contributes nothing in phase 3

    // ---- phase 3: gd[k] = W1[k,:]·g1 ; force += gd*cos(z0_k)*Wd[:,k] ----
    float f0 = 0.0f, f1 = 0.0f, f2 = 0.0f;
    for (int k = 0; k < NO; ++k) {
        float z0 = p0 * Wd[k] + p1 * Wd[NO + k] + p2 * Wd[2 * NO + k];
        float c = __cosf(z0);
        float gd;
        if (PADDED) {
            const float4* row = reinterpret_cast<const float4*>(w1s + k * HP);
            float a0 = 0.f, a1 = 0.f, a2 = 0.f, a3 = 0.f;  // 4 chains: hide fma latency
#pragma unroll
            for (int jj = 0; jj < HP / 4; ++jj) {
                float4 w = row[jj];
                a0 = fmaf(z1[4 * jj + 0], w.x, a0);
                a1 = fmaf(z1[4 * jj + 1], w.y, a1);
                a2 = fmaf(z1[4 * jj + 2], w.z, a2);
                a3 = fmaf(z1[4 * jj + 3], w.w, a3);
            }
            gd = (a0 + a1) + (a2 + a3);
        } else {
            const float* row = w1s + k * H;
            float a0 = 0.f, a1 = 0.f, a2 = 0.f, a3 = 0.f;
#pragma unroll
            for (int j = 0; j < H; ++j) {
                float v = fmaf(z1[j], row[j], 0.0f);
                if ((j & 3) == 0) a0 += v; else if ((j & 3) == 1) a1 += v;
                else if ((j & 3) == 2) a2 += v; else a3 += v;
            }
            gd = (a0 + a1) + (a2 + a3);
        }
        float gc = gd * c;
        f0 = fmaf(gc, Wd[k], f0);
        f1 = fmaf(gc, Wd[NO + k], f1);
        f2 = fmaf(gc, Wd[2 * NO + k], f2);
    }

    energies[atom] = es;
    forces[3 * atom + 0] = f0;
    forces[3 * atom + 1] = f1;
    forces[3 * atom + 2] = f2;
}

// ---------------------------------------------------------------------------
// Per-crystal energy: crystalidx is sorted in original atom order -> binary
// search segment bounds, strided sum, butterfly reduce. No atomics.
__global__ void crystal_energy(const int* __restrict__ cidx,
                               const float* __restrict__ energies,
                               float* __restrict__ energy, int n) {
    int c = blockIdx.x;
    int lane = threadIdx.x;           // 64 threads
    int lo = 0, hi = n;
    while (lo < hi) { int mid = (lo + hi) >> 1; if (cidx[mid] < c) lo = mid + 1; else hi = mid; }
    int start = lo;
    hi = n;
    while (lo < hi) { int mid = (lo + hi) >> 1; if (cidx[mid] < c + 1) lo = mid + 1; else hi = mid; }
    int end = lo;
    float sum = 0.0f;
    for (int i = start + lane; i < end; i += 64) sum += energies[i];
    for (int off = 32; off; off >>= 1) sum += __shfl_down(sum, off);
    if (lane == 0) energy[c] = sum;
}

// ---------------------------------------------------------------------------
extern "C" void kernel_launch(void* const* d_in, const int* in_sizes, int n_in,
                              void* d_out, int out_size, void* d_ws, size_t ws_size,
                              hipStream_t stream) {
    const int*   sym  = (const int*)d_in[0];
    const float* pos  = (const float*)d_in[1];
    // d_in[2] = cells  (unused by the stand-in descriptor)
    const int*   cidx = (const int*)d_in[3];
    // d_in[4] = pbcs   (unused)
    const float* Wd   = (const float*)d_in[5];
    const float* W1   = (const float*)d_in[6];
    const float* b1   = (const float*)d_in[7];
    const float* W2   = (const float*)d_in[8];
    const float* b2   = (const float*)d_in[9];

    int nta = in_sizes[0];
    int nc  = in_sizes[2] / 9;

    float* energies = (float*)d_out;          // [nta]
    float* energy   = energies + nta;         // [nc]
    float* forces   = energy + nc;            // [nta*3]

    // workspace layout: [w1p (S*NO*HP f32)] [counts u32x4] [cursors u32x4] [sorted i32[nta]]
    size_t w1p_bytes = (size_t)SP * NO * HP * sizeof(float);
    size_t need = w1p_bytes + 32 + (size_t)nta * sizeof(int);
    char* wsc = (char*)d_ws;
    float*    w1p     = (float*)wsc;
    unsigned* counts  = (unsigned*)(wsc + w1p_bytes);
    unsigned* cursors = counts + 4;
    int*      sorted  = (int*)(wsc + w1p_bytes + 32);

    if (ws_size >= need) {
        hipMemsetAsync(counts, 0, 32, stream);
        repack_w1<<<(SP * NO * HP + 255) / 256, 256, 0, stream>>>(W1, w1p);
        count_species<<<(nta + 255) / 256, 256, 0, stream>>>(sym, counts, nta);
        scan_species<<<1, 1, 0, stream>>>(counts, cursors);
        scatter_atoms<<<(nta + 511) / 512, 512, 0, stream>>>(sym, cursors, sorted, nta);
        atoms_kernel<true><<<(nta + 255) / 256, 256, 0, stream>>>(
            sorted, sym, pos, Wd, w1p, b1, W2, b2, energies, forces, nta);
    } else {
        // scratch too small for bucketing: correct (slower) fallback
        atoms_kernel<false><<<(nta + 255) / 256, 256, 0, stream>>>(
            nullptr, sym, pos, Wd, W1, b1, W2, b2, energies, forces, nta);
    }
    crystal_energy<<<nc, 64, 0, stream>>>(cidx, energies, energy, nta);
}

// Round 11
// 835.168 us; speedup vs baseline: 2.4757x; 2.4757x over previous
//
#include <hip/hip_runtime.h>
#include <math.h>

// Problem constants (match reference: NO=64, H=83, S=4)
#define NO 64
#define H  83
#define HP 84   // padded row stride (16B-aligned float4 rows)
#define SP 4    // species count

// ---------------------------------------------------------------------------
// Repack W1 [S][NO][H] -> w1p [S][NO][HP] with zero pad so rows are 16B-aligned
__global__ void repack_w1(const float* __restrict__ W1, float* __restrict__ w1p) {
    int idx = blockIdx.x * 256 + threadIdx.x;          // over S*NO*HP
    if (idx >= SP * NO * HP) return;
    int j  = idx % HP;
    int sk = idx / HP;                                  // s*NO + k
    w1p[idx] = (j < H) ? W1[sk * H + j] : 0.0f;
}

// ---------------------------------------------------------------------------
// Species histogram (block-aggregated atomics)
__global__ void count_species(const int* __restrict__ sym, unsigned* counts, int n) {
    __shared__ unsigned h[SP];
    if (threadIdx.x < SP) h[threadIdx.x] = 0;
    __syncthreads();
    int i = blockIdx.x * blockDim.x + threadIdx.x;
    if (i < n) atomicAdd(&h[sym[i]], 1u);
    __syncthreads();
    if (threadIdx.x < SP) atomicAdd(&counts[threadIdx.x], h[threadIdx.x]);
}

// Exclusive scan of 4 counts -> cursors
__global__ void scan_species(const unsigned* __restrict__ counts, unsigned* cursors) {
    unsigned acc = 0;
    for (int s = 0; s < SP; ++s) { cursors[s] = acc; acc += counts[s]; }
}

// Scatter atom ids into species-contiguous order (block-aggregated cursor atomics)
__global__ void scatter_atoms(const int* __restrict__ sym, unsigned* cursors,
                              int* __restrict__ sorted, int n) {
    __shared__ unsigned wcnt[8][SP];
    __shared__ unsigned wbase[8][SP];
    int lane = threadIdx.x & 63;
    int wave = threadIdx.x >> 6;
    int atom = blockIdx.x * 512 + threadIdx.x;
    int s = (atom < n) ? sym[atom] : -1;

    unsigned long long own = 0;
    for (int t = 0; t < SP; ++t) {
        unsigned long long m = __ballot(s == t);
        if (s == t) own = m;
        if (lane == 0) wcnt[wave][t] = (unsigned)__popcll(m);
    }
    __syncthreads();
    if (threadIdx.x < SP) {
        int t = threadIdx.x;
        unsigned tot = 0, pre[8];
        for (int w = 0; w < 8; ++w) { pre[w] = tot; tot += wcnt[w][t]; }
        unsigned base = atomicAdd(&cursors[t], tot);
        for (int w = 0; w < 8; ++w) wbase[w][t] = base + pre[w];
    }
    __syncthreads();
    if (atom < n) {
        unsigned rank = (unsigned)__popcll(own & ((1ull << lane) - 1ull));
        sorted[wbase[wave][s] + rank] = atom;
    }
}

// ---------------------------------------------------------------------------
// Main fused kernel: per-atom energy + force (fwd + analytic bwd).
// __launch_bounds__(256, 2): R1 postmortem — without it the backend targeted
// 8 waves/EU (64-VGPR cap) and spilled the whole z1[84] array to scratch
// (VGPR_Count=64, 4.8 GB HBM spill traffic, VALUBusy 10%). Cap 512/2=256
// VGPRs lets z1 live in registers; 2 waves/SIMD is enough TLP for a
// VALU-bound body with 4-way ILP accumulator chains.
template <bool PADDED>
__global__ void __launch_bounds__(256, 2)
atoms_kernel(const int* __restrict__ sorted,   // may be null
             const int* __restrict__ sym,
             const float* __restrict__ pos,
             const float* __restrict__ Wd,     // [3][NO]
             const float* __restrict__ w1,     // [S][NO][RS]
             const float* __restrict__ b1,     // [S][H]
             const float* __restrict__ W2,     // [S][H]
             const float* __restrict__ b2,     // [S]
             float* __restrict__ energies,
             float* __restrict__ forces,
             int n) {
    int slot = blockIdx.x * 256 + threadIdx.x;
    if (slot >= n) return;
    int atom = (sorted != nullptr) ? sorted[slot] : slot;
    int s = sym[atom];

    float p0 = pos[3 * atom + 0];
    float p1 = pos[3 * atom + 1];
    float p2 = pos[3 * atom + 2];

    constexpr int RS = PADDED ? HP : H;
    const float* w1s = w1 + (size_t)s * NO * RS;
    const float* b1s = b1 + s * H;
    const float* w2s = W2 + s * H;

    // z1 lives fully in registers: every index below is compile-time constant
    // after unrolling (no runtime indexing anywhere — rule #20).
    float z1[HP];
#pragma unroll
    for (int j = 0; j < H; ++j) z1[j] = b1s[j];
    z1[H] = 0.0f;

    // ---- phase 1: z1 = b1 + sin(p@Wd) @ W1  (k-outer, rows contiguous) ----
    for (int k = 0; k < NO; ++k) {
        float z0 = p0 * Wd[k] + p1 * Wd[NO + k] + p2 * Wd[2 * NO + k];
        float d = __sinf(z0);
        if (PADDED) {
            const float4* row = reinterpret_cast<const float4*>(w1s + k * HP);
#pragma unroll
            for (int jj = 0; jj < HP / 4; ++jj) {
                float4 w = row[jj];
                z1[4 * jj + 0] = fmaf(d, w.x, z1[4 * jj + 0]);
                z1[4 * jj + 1] = fmaf(d, w.y, z1[4 * jj + 1]);
                z1[4 * jj + 2] = fmaf(d, w.z, z1[4 * jj + 2]);
                z1[4 * jj + 3] = fmaf(d, w.w, z1[4 * jj + 3]);
            }
        } else {
            const float* row = w1s + k * H;
#pragma unroll
            for (int j = 0; j < H; ++j) z1[j] = fmaf(d, row[j], z1[j]);
        }
    }

    // ---- phase 2: SiLU, energy head, and g1 = W2 * silu'(z1) in place ----
    float es = b2[s];
#pragma unroll
    for (int j = 0; j < H; ++j) {
        float z  = z1[j];
        float sg = 1.0f / (1.0f + __expf(-z));
        float w2 = w2s[j];
        es = fmaf(z * sg, w2, es);
        // silu'(z) = sg * (1 + z*(1-sg))
        z1[j] = w2 * sg * fmaf(z, 1.0f - sg, 1.0f);
    }
    z1[H] = 0.0f;   // pad lane contributes nothing in phase 3

    // ---- phase 3: gd[k] = W1[k,:]·g1 ; force += gd*cos(z0_k)*Wd[:,k] ----
    float f0 = 0.0f, f1 = 0.0f, f2 = 0.0f;
    for (int k = 0; k < NO; ++k) {
        float z0 = p0 * Wd[k] + p1 * Wd[NO + k] + p2 * Wd[2 * NO + k];
        float c = __cosf(z0);
        float gd;
        if (PADDED) {
            const float4* row = reinterpret_cast<const float4*>(w1s + k * HP);
            float a0 = 0.f, a1 = 0.f, a2 = 0.f, a3 = 0.f;  // 4 chains: hide fma latency
#pragma unroll
            for (int jj = 0; jj < HP / 4; ++jj) {
                float4 w = row[jj];
                a0 = fmaf(z1[4 * jj + 0], w.x, a0);
                a1 = fmaf(z1[4 * jj + 1], w.y, a1);
                a2 = fmaf(z1[4 * jj + 2], w.z, a2);
                a3 = fmaf(z1[4 * jj + 3], w.w, a3);
            }
            gd = (a0 + a1) + (a2 + a3);
        } else {
            const float* row = w1s + k * H;
            float a0 = 0.f, a1 = 0.f, a2 = 0.f, a3 = 0.f;
#pragma unroll
            for (int j = 0; j < H; ++j) {
                float v = fmaf(z1[j], row[j], 0.0f);
                if ((j & 3) == 0) a0 += v; else if ((j & 3) == 1) a1 += v;
                else if ((j & 3) == 2) a2 += v; else a3 += v;
            }
            gd = (a0 + a1) + (a2 + a3);
        }
        float gc = gd * c;
        f0 = fmaf(gc, Wd[k], f0);
        f1 = fmaf(gc, Wd[NO + k], f1);
        f2 = fmaf(gc, Wd[2 * NO + k], f2);
    }

    energies[atom] = es;
    forces[3 * atom + 0] = f0;
    forces[3 * atom + 1] = f1;
    forces[3 * atom + 2] = f2;
}

// ---------------------------------------------------------------------------
// Per-crystal energy: crystalidx is sorted in original atom order -> binary
// search segment bounds, strided sum, butterfly reduce. No atomics.
__global__ void crystal_energy(const int* __restrict__ cidx,
                               const float* __restrict__ energies,
                               float* __restrict__ energy, int n) {
    int c = blockIdx.x;
    int lane = threadIdx.x;           // 64 threads
    int lo = 0, hi = n;
    while (lo < hi) { int mid = (lo + hi) >> 1; if (cidx[mid] < c) lo = mid + 1; else hi = mid; }
    int start = lo;
    hi = n;
    while (lo < hi) { int mid = (lo + hi) >> 1; if (cidx[mid] < c + 1) lo = mid + 1; else hi = mid; }
    int end = lo;
    float sum = 0.0f;
    for (int i = start + lane; i < end; i += 64) sum += energies[i];
    for (int off = 32; off; off >>= 1) sum += __shfl_down(sum, off);
    if (lane == 0) energy[c] = sum;
}

// ---------------------------------------------------------------------------
extern "C" void kernel_launch(void* const* d_in, const int* in_sizes, int n_in,
                              void* d_out, int out_size, void* d_ws, size_t ws_size,
                              hipStream_t stream) {
    const int*   sym  = (const int*)d_in[0];
    const float* pos  = (const float*)d_in[1];
    // d_in[2] = cells  (unused by the stand-in descriptor)
    const int*   cidx = (const int*)d_in[3];
    // d_in[4] = pbcs   (unused)
    const float* Wd   = (const float*)d_in[5];
    const float* W1   = (const float*)d_in[6];
    const float* b1   = (const float*)d_in[7];
    const float* W2   = (const float*)d_in[8];
    const float* b2   = (const float*)d_in[9];

    int nta = in_sizes[0];
    int nc  = in_sizes[2] / 9;

    float* energies = (float*)d_out;          // [nta]
    float* energy   = energies + nta;         // [nc]
    float* forces   = energy + nc;            // [nta*3]

    // workspace layout: [w1p (S*NO*HP f32)] [counts u32x4] [cursors u32x4] [sorted i32[nta]]
    size_t w1p_bytes = (size_t)SP * NO * HP * sizeof(float);
    size_t need = w1p_bytes + 32 + (size_t)nta * sizeof(int);
    char* wsc = (char*)d_ws;
    float*    w1p     = (float*)wsc;
    unsigned* counts  = (unsigned*)(wsc + w1p_bytes);
    unsigned* cursors = counts + 4;
    int*      sorted  = (int*)(wsc + w1p_bytes + 32);

    if (ws_size >= need) {
        hipMemsetAsync(counts, 0, 32, stream);
        repack_w1<<<(SP * NO * HP + 255) / 256, 256, 0, stream>>>(W1, w1p);
        count_species<<<(nta + 255) / 256, 256, 0, stream>>>(sym, counts, nta);
        scan_species<<<1, 1, 0, stream>>>(counts, cursors);
        scatter_atoms<<<(nta + 511) / 512, 512, 0, stream>>>(sym, cursors, sorted, nta);
        atoms_kernel<true><<<(nta + 255) / 256, 256, 0, stream>>>(
            sorted, sym, pos, Wd, w1p, b1, W2, b2, energies, forces, nta);
    } else {
        // scratch too small for bucketing: correct (slower) fallback
        atoms_kernel<false><<<(nta + 255) / 256, 256, 0, stream>>>(
            nullptr, sym, pos, Wd, W1, b1, W2, b2, energies, forces, nta);
    }
    crystal_energy<<<nc, 64, 0, stream>>>(cidx, energies, energy, nta);
}